// Round 5
// baseline (326.657 us; speedup 1.0000x reference)
//
#include <hip/hip_runtime.h>
#include <cmath>

#define T_LEN 48000
#define L_CHUNK 128
#define N_CHUNKS 375
#define N_ROWS 124
#define SLOTS 1024          // 8 channels * 128 padded rows
#define ROWS_PER_BLK 64
#define XS_STRIDE 132       // 128 + 4 pad floats: 528 B rows, 16B-aligned
#define TR_STRIDE 20        // 16 + 4 pad floats: 80 B rows, 16B-aligned
#define CBATCH 25
#define NBATCH 15           // CBATCH * NBATCH == N_CHUNKS
#define NBLK 250            // persistent blocks; 750 tiles / 250 = 3 each, all co-resident
#define NTILE 750

struct CoefF {
    float lp_b0, lp_b1, lp_b2, lp_a1, lp_a2;
    float bp_b0[7], bp_cr[7], bp_ci[7];
};
struct CoefD {
    double p00, p01, p10, p11;   // LP homogeneous propagator A^L
    double Pr[7], Pi[7];         // resonator propagators c^L
};

// Device-scope grid barrier. bar[0]=arrive counter, bar[1]=generation.
// Agent-scope acq/rel chain makes prior global stores visible cross-XCD.
__device__ __forceinline__ void gbar(unsigned* bar, unsigned nb) {
    __syncthreads();
    if (threadIdx.x == 0) {
        unsigned g = __hip_atomic_load(&bar[1], __ATOMIC_ACQUIRE, __HIP_MEMORY_SCOPE_AGENT);
        __threadfence();
        unsigned a = __hip_atomic_fetch_add(&bar[0], 1u, __ATOMIC_ACQ_REL, __HIP_MEMORY_SCOPE_AGENT);
        if (a == nb - 1u) {
            __hip_atomic_store(&bar[0], 0u, __ATOMIC_RELAXED, __HIP_MEMORY_SCOPE_AGENT);
            __hip_atomic_fetch_add(&bar[1], 1u, __ATOMIC_RELEASE, __HIP_MEMORY_SCOPE_AGENT);
        } else {
            while (__hip_atomic_load(&bar[1], __ATOMIC_ACQUIRE, __HIP_MEMORY_SCOPE_AGENT) == g)
                __builtin_amdgcn_s_sleep(8);
        }
    }
    __syncthreads();
}

// One 64-row x 128-sample tile. FINAL=false: emit chunk-final states only.
// FINAL=true: scan from corrected init state, transpose-store outputs.
template <bool FINAL>
__device__ __forceinline__ void process_tile(int tau, const float* __restrict__ x,
                                             const CoefF& C,
                                             float2* __restrict__ ws_fin,
                                             const float2* __restrict__ ws_init,
                                             float* __restrict__ out,
                                             float* __restrict__ smem) {
    float* xs = smem;                                  // [64][XS_STRIDE]
    const int t     = threadIdx.x;                     // 0..511
    const int j     = tau >> 1;                        // chunk index
    const int n0    = (tau & 1) * ROWS_PER_BLK;
    const int tbase = j * L_CHUNK;

    __syncthreads();   // previous tile's xs readers are done before we overwrite

    // ---- stage x tile into LDS, float4 both sides ----
#pragma unroll
    for (int i = 0; i < 4; ++i) {
        int g = i * 512 + t;            // float4-granule 0..2047
        int r = g >> 5, c = (g & 31) * 4;
        int n = n0 + r;
        float4 v = make_float4(0.f, 0.f, 0.f, 0.f);
        if (n < N_ROWS)
            v = *reinterpret_cast<const float4*>(x + (size_t)n * T_LEN + tbase + c);
        *reinterpret_cast<float4*>(xs + r * XS_STRIDE + c) = v;
    }
    __syncthreads();

    const int ch   = t >> 6;        // wave-uniform channel
    const int nn   = t & 63;        // lane = stream within tile
    const int n    = n0 + nn;
    const int widx = j * SLOTS + ch * 128 + n;
    float* trw = smem + ROWS_PER_BLK * XS_STRIDE + ch * (64 * TR_STRIDE);

    // wave-uniform coefficient selection (static indices)
    float f_b0, f_b1 = 0.f, f_b2 = 0.f, f_a1 = 0.f, f_a2 = 0.f, f_cr = 0.f, f_ci = 0.f;
    if (ch == 0) {
        f_b0 = C.lp_b0; f_b1 = C.lp_b1; f_b2 = C.lp_b2; f_a1 = C.lp_a1; f_a2 = C.lp_a2;
    } else {
        f_b0 = 0.f;
#pragma unroll
        for (int c = 1; c < 8; ++c)
            if (ch == c) { f_b0 = C.bp_b0[c - 1]; f_cr = C.bp_cr[c - 1]; f_ci = C.bp_ci[c - 1]; }
    }
    const bool kp = (ch <= 2);

    float s0 = 0.f, s1 = 0.f;
    if (FINAL) { float2 u = ws_init[widx]; s0 = u.x; s1 = u.y; }

    for (int b = 0; b < L_CHUNK / 16; ++b) {
        float4 xv4[4];
#pragma unroll
        for (int q = 0; q < 4; ++q)
            xv4[q] = *reinterpret_cast<const float4*>(xs + nn * XS_STRIDE + b * 16 + q * 4);
        const float* xv = reinterpret_cast<const float*>(xv4);

        float buf[16];
        if (ch == 0) {
#pragma unroll
            for (int k = 0; k < 16; ++k) {
                float xvk = xv[k];
                float y  = fmaf(f_b0, xvk, s0);
                s0 = fmaf(f_b1, xvk, fmaf(-f_a1, y, s1));
                s1 = fmaf(f_b2, xvk, -f_a2 * y);
                if (FINAL) buf[k] = 2.0f * y;
            }
        } else {
#pragma unroll
            for (int k = 0; k < 16; ++k) {
                float xvk = xv[k];
                float nyr = fmaf(f_cr, s0, fmaf(-f_ci, s1, f_b0 * xvk));
                float nyi = fmaf(f_cr, s1, f_ci * s0);
                s0 = nyr; s1 = nyi;
                if (FINAL)
                    buf[k] = kp ? 2.0f * nyr : 2.0f * sqrtf(fmaf(nyr, nyr, nyi * nyi));
            }
        }

        if (FINAL) {
            // per-wave transpose tile: rows = streams, cols = 16 samples
            asm volatile("s_waitcnt lgkmcnt(0)" ::: "memory");  // prev granule reads done
            *reinterpret_cast<float4*>(trw + nn * TR_STRIDE + 0)  = make_float4(buf[0], buf[1], buf[2], buf[3]);
            *reinterpret_cast<float4*>(trw + nn * TR_STRIDE + 4)  = make_float4(buf[4], buf[5], buf[6], buf[7]);
            *reinterpret_cast<float4*>(trw + nn * TR_STRIDE + 8)  = make_float4(buf[8], buf[9], buf[10], buf[11]);
            *reinterpret_cast<float4*>(trw + nn * TR_STRIDE + 12) = make_float4(buf[12], buf[13], buf[14], buf[15]);
            asm volatile("s_waitcnt lgkmcnt(0)" ::: "memory");  // tile visible wave-wide
#pragma unroll
            for (int s = 0; s < 4; ++s) {
                int rr = s * 16 + (nn >> 2);
                int kk = (nn & 3) * 4;
                int nrow = n0 + rr;
                if (nrow < N_ROWS) {
                    float4 v = *reinterpret_cast<const float4*>(trw + rr * TR_STRIDE + kk);
                    *reinterpret_cast<float4*>(out + (size_t)(nrow * 8 + ch) * T_LEN
                                               + tbase + b * 16 + kk) = v;
                }
            }
        }
    }
    if (!FINAL) ws_fin[widx] = make_float2(s0, s1);
}

// Sequential recomposition of chunk-boundary states (f64), software-pipelined.
__device__ __forceinline__ void combine_body(int s, const float2* __restrict__ ws_fin,
                                             float2* __restrict__ ws_init, const CoefD& D) {
    int ch = s >> 7;
    double m00, m01, m10, m11;
    if (ch == 0) {
        m00 = D.p00; m01 = D.p01; m10 = D.p10; m11 = D.p11;
    } else {
        double Pr = 0.0, Pi = 0.0;
#pragma unroll
        for (int c = 1; c < 8; ++c) if (ch == c) { Pr = D.Pr[c - 1]; Pi = D.Pi[c - 1]; }
        m00 = Pr; m01 = -Pi; m10 = Pi; m11 = Pr;
    }

    double u0 = 0.0, u1 = 0.0;
    const float2* base = ws_fin + s;
    float2 fa[CBATCH], fb[CBATCH];

    auto LOAD = [&](float2 (&f)[CBATCH], int jbase) {
#pragma unroll
        for (int i = 0; i < CBATCH; ++i) f[i] = base[(size_t)(jbase + i) * SLOTS];
    };
    auto PROC = [&](const float2 (&f)[CBATCH], int jbase) {
#pragma unroll
        for (int i = 0; i < CBATCH; ++i) {
            ws_init[(size_t)(jbase + i) * SLOTS + s] = make_float2((float)u0, (float)u1);
            double t0 = (double)f[i].x + m00 * u0 + m01 * u1;
            double t1 = (double)f[i].y + m10 * u0 + m11 * u1;
            u0 = t0; u1 = t1;
        }
    };

    LOAD(fa, 0);
    for (int bt = 0; bt < NBATCH; bt += 2) {
        if (bt + 1 < NBATCH) LOAD(fb, (bt + 1) * CBATCH);
        PROC(fa, bt * CBATCH);
        if (bt + 2 < NBATCH) LOAD(fa, (bt + 2) * CBATCH);
        if (bt + 1 < NBATCH) PROC(fb, (bt + 1) * CBATCH);
    }
}

// Single persistent kernel: phase1 -> grid barrier -> combine -> grid barrier -> phase3.
// 250 blocks, 74.75 KB LDS (>=2 blocks/CU capacity => all co-resident, no deadlock).
__global__ __launch_bounds__(512, 2) void mfb_fused(const float* __restrict__ x,
                                                    CoefF C, CoefD D,
                                                    float2* __restrict__ ws_fin,
                                                    float2* __restrict__ ws_init,
                                                    float* __restrict__ out,
                                                    unsigned* __restrict__ bar) {
    extern __shared__ __align__(16) float smem[];
    const int bid = blockIdx.x;

    for (int tau = bid; tau < NTILE; tau += NBLK)
        process_tile<false>(tau, x, C, ws_fin, nullptr, nullptr, smem);

    gbar(bar, NBLK);

    if (bid < 2)
        combine_body(bid * 512 + (int)threadIdx.x, ws_fin, ws_init, D);

    gbar(bar, NBLK);

    for (int tau = bid; tau < NTILE; tau += NBLK)
        process_tile<true>(tau, x, C, nullptr, ws_init, out, smem);
}

extern "C" void kernel_launch(void* const* d_in, const int* in_sizes, int n_in,
                              void* d_out, int out_size, void* d_ws, size_t ws_size,
                              hipStream_t stream) {
    const float* x = (const float*)d_in[0];
    float* out = (float*)d_out;
    char* ws = (char*)d_ws;
    float2* ws_fin  = (float2*)ws;                     // 3,072,000 B
    float2* ws_init = (float2*)(ws + 3072000);         // 3,072,000 B
    unsigned* bar   = (unsigned*)(ws + 6144000);       // 8 B

    // ---- host-side coefficient computation (double, cast to f32 like the ref) ----
    const double PI = 3.141592653589793;
    const double FS = 16000.0;
    CoefF C; CoefD D;
    {
        double K   = tan(PI * 2.5 / FS);
        double nrm = 1.0 / (1.0 + sqrt(2.0) * K + K * K);
        double a1  = 2.0 * (K * K - 1.0) * nrm;
        double a2  = (1.0 - sqrt(2.0) * K + K * K) * nrm;
        C.lp_b0 = (float)(K * K * nrm);
        C.lp_b1 = (float)(2.0 * K * K * nrm);
        C.lp_b2 = (float)(K * K * nrm);
        C.lp_a1 = (float)a1;
        C.lp_a2 = (float)a2;
        double p00 = -a1, p01 = 1.0, p10 = -a2, p11 = 0.0;
        for (int i = 0; i < 7; ++i) {   // A^128 by 7 squarings
            double q00 = p00 * p00 + p01 * p10, q01 = p00 * p01 + p01 * p11;
            double q10 = p10 * p00 + p11 * p10, q11 = p10 * p01 + p11 * p11;
            p00 = q00; p01 = q01; p10 = q10; p11 = q11;
        }
        D.p00 = p00; D.p01 = p01; D.p10 = p10; D.p11 = p11;

        double r = (1.0 + 1.0 / 4.0) / (1.0 - 1.0 / 4.0);   // 5/3
        double mfc[7]; mfc[0] = 5.0; mfc[1] = 10.0;
        double f = 10.0 * r;
        for (int m = 2; m < 7; ++m) { mfc[m] = f; f *= r; }
        for (int m = 0; m < 7; ++m) {
            double bw = (mfc[m] <= 10.0) ? 5.0 : mfc[m] * 0.5;
            double e0 = exp(-PI * bw / FS);
            double th = 2.0 * PI * mfc[m] / FS;
            C.bp_b0[m] = (float)(1.0 - e0);
            C.bp_cr[m] = (float)(e0 * cos(th));
            C.bp_ci[m] = (float)(e0 * sin(th));
            double eL  = exp(-PI * bw * (double)L_CHUNK / FS);
            double ang = th * (double)L_CHUNK;
            D.Pr[m] = eL * cos(ang);
            D.Pi[m] = eL * sin(ang);
        }
    }

    const int smem3 = ROWS_PER_BLK * XS_STRIDE * 4 + 8 * 64 * TR_STRIDE * 4;  // 74752 B
    hipMemsetAsync(bar, 0, 8, stream);   // barrier state must start at zero each call
    mfb_fused<<<NBLK, 512, smem3, stream>>>(x, C, D, ws_fin, ws_init, out, bar);
}

// Round 6
// 132.724 us; speedup vs baseline: 2.4612x; 2.4612x over previous
//
#include <hip/hip_runtime.h>
#include <cmath>

#define T_LEN 48000
#define L_CHUNK 128
#define N_CHUNKS 375
#define N_ROWS 124
#define SLOTS 1024          // 8 channels * 128 padded rows
#define ROWS_PER_BLK 64
#define XS_STRIDE 132       // 128 + 4 pad floats: 528 B rows, 16B-aligned
#define TR_STRIDE 20        // 16 + 4 pad floats: 80 B rows, 16B-aligned
#define CBATCH 15           // 30 VGPRs live in combine -- spill-proof
#define NROUND 25           // CBATCH * NROUND == N_CHUNKS
#define NBLK 250            // persistent blocks; 750 tiles / 250 = 3 each, all co-resident
#define NTILE 750

struct CoefF {
    float lp_b0, lp_b1, lp_b2, lp_a1, lp_a2;
    float bp_b0[7], bp_cr[7], bp_ci[7];
};
struct CoefD {
    double p00, p01, p10, p11;   // LP homogeneous propagator A^L
    double Pr[7], Pi[7];         // resonator propagators c^L
};

// Grid barrier. bar[0]=arrive counter, bar[1]=generation.
// Spin uses RELAXED agent loads (reads coherence point, NO per-poll cache
// invalidate); a single ACQUIRE fence after exit pairs with the RELEASE RMWs
// to make prior global stores visible cross-XCD.
__device__ __forceinline__ void gbar(unsigned* bar, unsigned nb) {
    __syncthreads();
    if (threadIdx.x == 0) {
        unsigned g = __hip_atomic_load(&bar[1], __ATOMIC_RELAXED, __HIP_MEMORY_SCOPE_AGENT);
        unsigned a = __hip_atomic_fetch_add(&bar[0], 1u, __ATOMIC_RELEASE, __HIP_MEMORY_SCOPE_AGENT);
        if (a == nb - 1u) {
            __hip_atomic_store(&bar[0], 0u, __ATOMIC_RELAXED, __HIP_MEMORY_SCOPE_AGENT);
            __hip_atomic_fetch_add(&bar[1], 1u, __ATOMIC_RELEASE, __HIP_MEMORY_SCOPE_AGENT);
        } else {
            while (__hip_atomic_load(&bar[1], __ATOMIC_RELAXED, __HIP_MEMORY_SCOPE_AGENT) == g)
                __builtin_amdgcn_s_sleep(16);
        }
        __builtin_amdgcn_fence(__ATOMIC_ACQUIRE, "agent");
    }
    __syncthreads();
}

// One 64-row x 128-sample tile. FINAL=false: emit chunk-final states only.
// FINAL=true: scan from corrected init state, transpose-store outputs.
template <bool FINAL>
__device__ __forceinline__ void process_tile(int tau, const float* __restrict__ x,
                                             const CoefF& C,
                                             float2* __restrict__ ws_fin,
                                             const float2* __restrict__ ws_init,
                                             float* __restrict__ out,
                                             float* __restrict__ smem) {
    float* xs = smem;                                  // [64][XS_STRIDE]
    const int t     = threadIdx.x;                     // 0..511
    const int j     = tau >> 1;                        // chunk index
    const int n0    = (tau & 1) * ROWS_PER_BLK;
    const int tbase = j * L_CHUNK;

    __syncthreads();   // previous tile's xs readers are done before we overwrite

    // ---- stage x tile into LDS, float4 both sides ----
#pragma unroll
    for (int i = 0; i < 4; ++i) {
        int g = i * 512 + t;            // float4-granule 0..2047
        int r = g >> 5, c = (g & 31) * 4;
        int n = n0 + r;
        float4 v = make_float4(0.f, 0.f, 0.f, 0.f);
        if (n < N_ROWS)
            v = *reinterpret_cast<const float4*>(x + (size_t)n * T_LEN + tbase + c);
        *reinterpret_cast<float4*>(xs + r * XS_STRIDE + c) = v;
    }
    __syncthreads();

    const int ch   = t >> 6;        // wave-uniform channel
    const int nn   = t & 63;        // lane = stream within tile
    const int n    = n0 + nn;
    const int widx = j * SLOTS + ch * 128 + n;
    float* trw = smem + ROWS_PER_BLK * XS_STRIDE + ch * (64 * TR_STRIDE);

    // wave-uniform coefficient selection (static indices)
    float f_b0, f_b1 = 0.f, f_b2 = 0.f, f_a1 = 0.f, f_a2 = 0.f, f_cr = 0.f, f_ci = 0.f;
    if (ch == 0) {
        f_b0 = C.lp_b0; f_b1 = C.lp_b1; f_b2 = C.lp_b2; f_a1 = C.lp_a1; f_a2 = C.lp_a2;
    } else {
        f_b0 = 0.f;
#pragma unroll
        for (int c = 1; c < 8; ++c)
            if (ch == c) { f_b0 = C.bp_b0[c - 1]; f_cr = C.bp_cr[c - 1]; f_ci = C.bp_ci[c - 1]; }
    }
    const bool kp = (ch <= 2);

    float s0 = 0.f, s1 = 0.f;
    if (FINAL) { float2 u = ws_init[widx]; s0 = u.x; s1 = u.y; }

    for (int b = 0; b < L_CHUNK / 16; ++b) {
        float4 xv4[4];
#pragma unroll
        for (int q = 0; q < 4; ++q)
            xv4[q] = *reinterpret_cast<const float4*>(xs + nn * XS_STRIDE + b * 16 + q * 4);
        const float* xv = reinterpret_cast<const float*>(xv4);

        float buf[16];
        if (ch == 0) {
#pragma unroll
            for (int k = 0; k < 16; ++k) {
                float xvk = xv[k];
                float y  = fmaf(f_b0, xvk, s0);
                s0 = fmaf(f_b1, xvk, fmaf(-f_a1, y, s1));
                s1 = fmaf(f_b2, xvk, -f_a2 * y);
                if (FINAL) buf[k] = 2.0f * y;
            }
        } else {
#pragma unroll
            for (int k = 0; k < 16; ++k) {
                float xvk = xv[k];
                float nyr = fmaf(f_cr, s0, fmaf(-f_ci, s1, f_b0 * xvk));
                float nyi = fmaf(f_cr, s1, f_ci * s0);
                s0 = nyr; s1 = nyi;
                if (FINAL)
                    buf[k] = kp ? 2.0f * nyr : 2.0f * sqrtf(fmaf(nyr, nyr, nyi * nyi));
            }
        }

        if (FINAL) {
            // per-wave transpose tile: rows = streams, cols = 16 samples
            asm volatile("s_waitcnt lgkmcnt(0)" ::: "memory");  // prev granule reads done
            *reinterpret_cast<float4*>(trw + nn * TR_STRIDE + 0)  = make_float4(buf[0], buf[1], buf[2], buf[3]);
            *reinterpret_cast<float4*>(trw + nn * TR_STRIDE + 4)  = make_float4(buf[4], buf[5], buf[6], buf[7]);
            *reinterpret_cast<float4*>(trw + nn * TR_STRIDE + 8)  = make_float4(buf[8], buf[9], buf[10], buf[11]);
            *reinterpret_cast<float4*>(trw + nn * TR_STRIDE + 12) = make_float4(buf[12], buf[13], buf[14], buf[15]);
            asm volatile("s_waitcnt lgkmcnt(0)" ::: "memory");  // tile visible wave-wide
#pragma unroll
            for (int s = 0; s < 4; ++s) {
                int rr = s * 16 + (nn >> 2);
                int kk = (nn & 3) * 4;
                int nrow = n0 + rr;
                if (nrow < N_ROWS) {
                    float4 v = *reinterpret_cast<const float4*>(trw + rr * TR_STRIDE + kk);
                    *reinterpret_cast<float4*>(out + (size_t)(nrow * 8 + ch) * T_LEN
                                               + tbase + b * 16 + kk) = v;
                }
            }
        }
    }
    if (!FINAL) ws_fin[widx] = make_float2(s0, s1);
}

// Sequential recomposition of chunk-boundary states (f64).
// Single-buffer batches of CBATCH=15: max ~50 VGPRs live -> no scratch spill.
__device__ __forceinline__ void combine_body(int s, const float2* __restrict__ ws_fin,
                                             float2* __restrict__ ws_init, const CoefD& D) {
    int ch = s >> 7;
    double m00, m01, m10, m11;
    if (ch == 0) {
        m00 = D.p00; m01 = D.p01; m10 = D.p10; m11 = D.p11;
    } else {
        double Pr = 0.0, Pi = 0.0;
#pragma unroll
        for (int c = 1; c < 8; ++c) if (ch == c) { Pr = D.Pr[c - 1]; Pi = D.Pi[c - 1]; }
        m00 = Pr; m01 = -Pi; m10 = Pi; m11 = Pr;
    }

    double u0 = 0.0, u1 = 0.0;
    const float2* base = ws_fin + s;
    for (int r = 0; r < NROUND; ++r) {
        float2 f[CBATCH];
#pragma unroll
        for (int i = 0; i < CBATCH; ++i)
            f[i] = base[(size_t)(r * CBATCH + i) * SLOTS];
#pragma unroll
        for (int i = 0; i < CBATCH; ++i) {
            ws_init[(size_t)(r * CBATCH + i) * SLOTS + s] = make_float2((float)u0, (float)u1);
            double t0 = (double)f[i].x + m00 * u0 + m01 * u1;
            double t1 = (double)f[i].y + m10 * u0 + m11 * u1;
            u0 = t0; u1 = t1;
        }
    }
}

// Single persistent kernel: phase1 -> grid barrier -> combine -> grid barrier -> phase3.
// 250 blocks, 74.75 KB LDS (2 blocks/CU capacity => all co-resident, no deadlock).
// waves_per_eu(4,4): allocator targets exactly 4 waves/EU (the LDS cap) -> up to
// 128 VGPRs with no incentive to shrink-and-spill (R5: it chose 68 and spilled).
__global__ __launch_bounds__(512) __attribute__((amdgpu_waves_per_eu(4, 4)))
void mfb_fused(const float* __restrict__ x,
               CoefF C, CoefD D,
               float2* __restrict__ ws_fin,
               float2* __restrict__ ws_init,
               float* __restrict__ out,
               unsigned* __restrict__ bar) {
    extern __shared__ __align__(16) float smem[];
    const int bid = blockIdx.x;

    for (int tau = bid; tau < NTILE; tau += NBLK)
        process_tile<false>(tau, x, C, ws_fin, nullptr, nullptr, smem);

    gbar(bar, NBLK);

    if (bid < 2)
        combine_body(bid * 512 + (int)threadIdx.x, ws_fin, ws_init, D);

    gbar(bar, NBLK);

    for (int tau = bid; tau < NTILE; tau += NBLK)
        process_tile<true>(tau, x, C, nullptr, ws_init, out, smem);
}

extern "C" void kernel_launch(void* const* d_in, const int* in_sizes, int n_in,
                              void* d_out, int out_size, void* d_ws, size_t ws_size,
                              hipStream_t stream) {
    const float* x = (const float*)d_in[0];
    float* out = (float*)d_out;
    char* ws = (char*)d_ws;
    float2* ws_fin  = (float2*)ws;                     // 3,072,000 B
    float2* ws_init = (float2*)(ws + 3072000);         // 3,072,000 B
    unsigned* bar   = (unsigned*)(ws + 6144000);       // 8 B

    // ---- host-side coefficient computation (double, cast to f32 like the ref) ----
    const double PI = 3.141592653589793;
    const double FS = 16000.0;
    CoefF C; CoefD D;
    {
        double K   = tan(PI * 2.5 / FS);
        double nrm = 1.0 / (1.0 + sqrt(2.0) * K + K * K);
        double a1  = 2.0 * (K * K - 1.0) * nrm;
        double a2  = (1.0 - sqrt(2.0) * K + K * K) * nrm;
        C.lp_b0 = (float)(K * K * nrm);
        C.lp_b1 = (float)(2.0 * K * K * nrm);
        C.lp_b2 = (float)(K * K * nrm);
        C.lp_a1 = (float)a1;
        C.lp_a2 = (float)a2;
        double p00 = -a1, p01 = 1.0, p10 = -a2, p11 = 0.0;
        for (int i = 0; i < 7; ++i) {   // A^128 by 7 squarings
            double q00 = p00 * p00 + p01 * p10, q01 = p00 * p01 + p01 * p11;
            double q10 = p10 * p00 + p11 * p10, q11 = p10 * p01 + p11 * p11;
            p00 = q00; p01 = q01; p10 = q10; p11 = q11;
        }
        D.p00 = p00; D.p01 = p01; D.p10 = p10; D.p11 = p11;

        double r = (1.0 + 1.0 / 4.0) / (1.0 - 1.0 / 4.0);   // 5/3
        double mfc[7]; mfc[0] = 5.0; mfc[1] = 10.0;
        double f = 10.0 * r;
        for (int m = 2; m < 7; ++m) { mfc[m] = f; f *= r; }
        for (int m = 0; m < 7; ++m) {
            double bw = (mfc[m] <= 10.0) ? 5.0 : mfc[m] * 0.5;
            double e0 = exp(-PI * bw / FS);
            double th = 2.0 * PI * mfc[m] / FS;
            C.bp_b0[m] = (float)(1.0 - e0);
            C.bp_cr[m] = (float)(e0 * cos(th));
            C.bp_ci[m] = (float)(e0 * sin(th));
            double eL  = exp(-PI * bw * (double)L_CHUNK / FS);
            double ang = th * (double)L_CHUNK;
            D.Pr[m] = eL * cos(ang);
            D.Pi[m] = eL * sin(ang);
        }
    }

    const int smem3 = ROWS_PER_BLK * XS_STRIDE * 4 + 8 * 64 * TR_STRIDE * 4;  // 74752 B
    hipMemsetAsync(bar, 0, 8, stream);   // barrier state must start at zero each call
    mfb_fused<<<NBLK, 512, smem3, stream>>>(x, C, D, ws_fin, ws_init, out, bar);
}

// Round 7
// 70.786 us; speedup vs baseline: 4.6147x; 1.8750x over previous
//
#include <hip/hip_runtime.h>
#include <cmath>

#define T_LEN 48000
#define L_CHUNK 128
#define N_CHUNKS 375
#define N_ROWS 124
#define SLOTS 1024          // 8 channels * 128 padded rows
#define ROWS_PER_BLK 64
#define XS_STRIDE 132       // 128 + 4 pad floats: 528 B rows, 16B-aligned
#define TR_STRIDE 20        // 16 + 4 pad floats: 80 B rows, 16B-aligned
#define GRP 15              // chunks per group
#define NGRP 25             // groups: GRP * NGRP == N_CHUNKS

struct CoefF {
    float lp_b0, lp_b1, lp_b2, lp_a1, lp_a2;
    float bp_b0[7], bp_cr[7], bp_ci[7];
};
struct CoefD {
    double p00, p01, p10, p11;   // LP propagator (2x2)
    double Pr[7], Pi[7];         // resonator propagators (complex)
};

// Select per-channel propagator as real 2x2 (wave-uniform ch, static indices).
__device__ __forceinline__ void sel_M(int ch, const CoefD& D,
                                      double& m00, double& m01, double& m10, double& m11) {
    if (ch == 0) {
        m00 = D.p00; m01 = D.p01; m10 = D.p10; m11 = D.p11;
    } else {
        double Pr = 0.0, Pi = 0.0;
#pragma unroll
        for (int c = 1; c < 8; ++c) if (ch == c) { Pr = D.Pr[c - 1]; Pi = D.Pi[c - 1]; }
        m00 = Pr; m01 = -Pi; m10 = Pi; m11 = Pr;
    }
}

// Phase 1 (FINAL=false): zero-init chunk scan, write final state only.
// Phase 3 (FINAL=true):  scan from corrected init state, transpose-store outputs.
template <bool FINAL>
__global__ __launch_bounds__(512) void mfb_chunk(const float* __restrict__ x,
                                                 CoefF C,
                                                 float2* __restrict__ ws_fin,
                                                 const float2* __restrict__ ws_init,
                                                 float* __restrict__ out) {
    extern __shared__ __align__(16) float smem[];
    float* xs = smem;                                  // [64][XS_STRIDE]
    const int t     = threadIdx.x;                     // 0..511
    const int j     = blockIdx.y;                      // chunk index
    const int n0    = (int)blockIdx.x * ROWS_PER_BLK;
    const int tbase = j * L_CHUNK;

    // ---- stage x tile into LDS, float4 both sides ----
#pragma unroll
    for (int i = 0; i < 4; ++i) {
        int g = i * 512 + t;            // float4-granule 0..2047
        int r = g >> 5, c = (g & 31) * 4;
        int n = n0 + r;
        float4 v = make_float4(0.f, 0.f, 0.f, 0.f);
        if (n < N_ROWS)
            v = *reinterpret_cast<const float4*>(x + (size_t)n * T_LEN + tbase + c);
        *reinterpret_cast<float4*>(xs + r * XS_STRIDE + c) = v;
    }
    __syncthreads();

    const int ch   = t >> 6;        // wave-uniform channel
    const int nn   = t & 63;        // lane = stream within tile
    const int n    = n0 + nn;
    const int widx = j * SLOTS + ch * 128 + n;
    float* trw = smem + ROWS_PER_BLK * XS_STRIDE + ch * (64 * TR_STRIDE);

    float f_b0, f_b1 = 0.f, f_b2 = 0.f, f_a1 = 0.f, f_a2 = 0.f, f_cr = 0.f, f_ci = 0.f;
    if (ch == 0) {
        f_b0 = C.lp_b0; f_b1 = C.lp_b1; f_b2 = C.lp_b2; f_a1 = C.lp_a1; f_a2 = C.lp_a2;
    } else {
        f_b0 = 0.f;
#pragma unroll
        for (int c = 1; c < 8; ++c)
            if (ch == c) { f_b0 = C.bp_b0[c - 1]; f_cr = C.bp_cr[c - 1]; f_ci = C.bp_ci[c - 1]; }
    }
    const bool kp = (ch <= 2);

    float s0 = 0.f, s1 = 0.f;
    if (FINAL) { float2 u = ws_init[widx]; s0 = u.x; s1 = u.y; }

    for (int b = 0; b < L_CHUNK / 16; ++b) {
        float4 xv4[4];
#pragma unroll
        for (int q = 0; q < 4; ++q)
            xv4[q] = *reinterpret_cast<const float4*>(xs + nn * XS_STRIDE + b * 16 + q * 4);
        const float* xv = reinterpret_cast<const float*>(xv4);

        float buf[16];
        if (ch == 0) {
#pragma unroll
            for (int k = 0; k < 16; ++k) {
                float xvk = xv[k];
                float y  = fmaf(f_b0, xvk, s0);
                s0 = fmaf(f_b1, xvk, fmaf(-f_a1, y, s1));
                s1 = fmaf(f_b2, xvk, -f_a2 * y);
                if (FINAL) buf[k] = 2.0f * y;
            }
        } else {
#pragma unroll
            for (int k = 0; k < 16; ++k) {
                float xvk = xv[k];
                float nyr = fmaf(f_cr, s0, fmaf(-f_ci, s1, f_b0 * xvk));
                float nyi = fmaf(f_cr, s1, f_ci * s0);
                s0 = nyr; s1 = nyi;
                if (FINAL)
                    buf[k] = kp ? 2.0f * nyr : 2.0f * sqrtf(fmaf(nyr, nyr, nyi * nyi));
            }
        }

        if (FINAL) {
            asm volatile("s_waitcnt lgkmcnt(0)" ::: "memory");  // prev granule reads done
            *reinterpret_cast<float4*>(trw + nn * TR_STRIDE + 0)  = make_float4(buf[0], buf[1], buf[2], buf[3]);
            *reinterpret_cast<float4*>(trw + nn * TR_STRIDE + 4)  = make_float4(buf[4], buf[5], buf[6], buf[7]);
            *reinterpret_cast<float4*>(trw + nn * TR_STRIDE + 8)  = make_float4(buf[8], buf[9], buf[10], buf[11]);
            *reinterpret_cast<float4*>(trw + nn * TR_STRIDE + 12) = make_float4(buf[12], buf[13], buf[14], buf[15]);
            asm volatile("s_waitcnt lgkmcnt(0)" ::: "memory");  // tile visible wave-wide
#pragma unroll
            for (int s = 0; s < 4; ++s) {
                int rr = s * 16 + (nn >> 2);
                int kk = (nn & 3) * 4;
                int nrow = n0 + rr;
                if (nrow < N_ROWS) {
                    float4 v = *reinterpret_cast<const float4*>(trw + rr * TR_STRIDE + kk);
                    *reinterpret_cast<float4*>(out + (size_t)(nrow * 8 + ch) * T_LEN
                                               + tbase + b * 16 + kk) = v;
                }
            }
        }
    }
    if (!FINAL) ws_fin[widx] = make_float2(s0, s1);
}

// ---- Tree combine, stage A: per (slot, group) aggregate A_g = sum M^(14-i) F_i ----
__global__ __launch_bounds__(256) void mfb_groupsum(const float2* __restrict__ ws_fin,
                                                    float2* __restrict__ A, CoefD D) {
    int tid = blockIdx.x * 256 + (int)threadIdx.x;   // 0..25599
    int s = tid & 1023, g = tid >> 10;
    double m00, m01, m10, m11;
    sel_M(s >> 7, D, m00, m01, m10, m11);

    const float2* base = ws_fin + (size_t)g * GRP * SLOTS + s;
    float2 f[GRP];
#pragma unroll
    for (int i = 0; i < GRP; ++i) f[i] = base[(size_t)i * SLOTS];

    double a0 = 0.0, a1 = 0.0;
#pragma unroll
    for (int i = 0; i < GRP; ++i) {
        double t0 = m00 * a0 + m01 * a1 + (double)f[i].x;
        double t1 = m10 * a0 + m11 * a1 + (double)f[i].y;
        a0 = t0; a1 = t1;
    }
    A[(size_t)g * SLOTS + s] = make_float2((float)a0, (float)a1);
}

// ---- stage B: per slot, exclusive prefix over 25 groups with M15 = M^(15*128) ----
__global__ __launch_bounds__(256) void mfb_groupscan(const float2* __restrict__ A,
                                                     float2* __restrict__ U, CoefD D15) {
    int s = blockIdx.x * 256 + (int)threadIdx.x;     // 0..1023
    double m00, m01, m10, m11;
    sel_M(s >> 7, D15, m00, m01, m10, m11);

    float2 f[NGRP];
#pragma unroll
    for (int g = 0; g < NGRP; ++g) f[g] = A[(size_t)g * SLOTS + s];

    double u0 = 0.0, u1 = 0.0;
#pragma unroll
    for (int g = 0; g < NGRP; ++g) {
        U[(size_t)g * SLOTS + s] = make_float2((float)u0, (float)u1);
        double t0 = (double)f[g].x + m00 * u0 + m01 * u1;
        double t1 = (double)f[g].y + m10 * u0 + m11 * u1;
        u0 = t0; u1 = t1;
    }
}

// ---- stage C: per (slot, group) expand: write all 15 chunk-init states ----
__global__ __launch_bounds__(256) void mfb_expand(const float2* __restrict__ ws_fin,
                                                  const float2* __restrict__ U,
                                                  float2* __restrict__ ws_init, CoefD D) {
    int tid = blockIdx.x * 256 + (int)threadIdx.x;   // 0..25599
    int s = tid & 1023, g = tid >> 10;
    double m00, m01, m10, m11;
    sel_M(s >> 7, D, m00, m01, m10, m11);

    const float2* base = ws_fin + (size_t)g * GRP * SLOTS + s;
    float2 f[GRP];
#pragma unroll
    for (int i = 0; i < GRP; ++i) f[i] = base[(size_t)i * SLOTS];

    float2 ug = U[(size_t)g * SLOTS + s];
    double u0 = ug.x, u1 = ug.y;
#pragma unroll
    for (int i = 0; i < GRP; ++i) {
        ws_init[(size_t)(g * GRP + i) * SLOTS + s] = make_float2((float)u0, (float)u1);
        double t0 = (double)f[i].x + m00 * u0 + m01 * u1;
        double t1 = (double)f[i].y + m10 * u0 + m11 * u1;
        u0 = t0; u1 = t1;
    }
}

extern "C" void kernel_launch(void* const* d_in, const int* in_sizes, int n_in,
                              void* d_out, int out_size, void* d_ws, size_t ws_size,
                              hipStream_t stream) {
    const float* x = (const float*)d_in[0];
    float* out = (float*)d_out;
    char* ws = (char*)d_ws;
    float2* ws_fin  = (float2*)ws;                     // 3,072,000 B
    float2* ws_init = (float2*)(ws + 3072000);         // 3,072,000 B
    float2* Agg     = (float2*)(ws + 6144000);         //   204,800 B
    float2* Upre    = (float2*)(ws + 6348800);         //   204,800 B

    // ---- host-side coefficient computation (double, cast to f32 like the ref) ----
    const double PI = 3.141592653589793;
    const double FS = 16000.0;
    CoefF C; CoefD D, D15;
    {
        double K   = tan(PI * 2.5 / FS);
        double nrm = 1.0 / (1.0 + sqrt(2.0) * K + K * K);
        double a1  = 2.0 * (K * K - 1.0) * nrm;
        double a2  = (1.0 - sqrt(2.0) * K + K * K) * nrm;
        C.lp_b0 = (float)(K * K * nrm);
        C.lp_b1 = (float)(2.0 * K * K * nrm);
        C.lp_b2 = (float)(K * K * nrm);
        C.lp_a1 = (float)a1;
        C.lp_a2 = (float)a2;
        double p00 = -a1, p01 = 1.0, p10 = -a2, p11 = 0.0;
        for (int i = 0; i < 7; ++i) {   // A^128 by 7 squarings
            double q00 = p00 * p00 + p01 * p10, q01 = p00 * p01 + p01 * p11;
            double q10 = p10 * p00 + p11 * p10, q11 = p10 * p01 + p11 * p11;
            p00 = q00; p01 = q01; p10 = q10; p11 = q11;
        }
        D.p00 = p00; D.p01 = p01; D.p10 = p10; D.p11 = p11;
        // (A^128)^15 by square-and-multiply (15 = 1111b)
        double r00 = 1, r01 = 0, r10 = 0, r11 = 1, b00 = p00, b01 = p01, b10 = p10, b11 = p11;
        for (int e = 15; e > 0; e >>= 1) {
            if (e & 1) {
                double q00 = r00 * b00 + r01 * b10, q01 = r00 * b01 + r01 * b11;
                double q10 = r10 * b00 + r11 * b10, q11 = r10 * b01 + r11 * b11;
                r00 = q00; r01 = q01; r10 = q10; r11 = q11;
            }
            double q00 = b00 * b00 + b01 * b10, q01 = b00 * b01 + b01 * b11;
            double q10 = b10 * b00 + b11 * b10, q11 = b10 * b01 + b11 * b11;
            b00 = q00; b01 = q01; b10 = q10; b11 = q11;
        }
        D15.p00 = r00; D15.p01 = r01; D15.p10 = r10; D15.p11 = r11;

        double rr = (1.0 + 1.0 / 4.0) / (1.0 - 1.0 / 4.0);   // 5/3
        double mfc[7]; mfc[0] = 5.0; mfc[1] = 10.0;
        double f = 10.0 * rr;
        for (int m = 2; m < 7; ++m) { mfc[m] = f; f *= rr; }
        for (int m = 0; m < 7; ++m) {
            double bw = (mfc[m] <= 10.0) ? 5.0 : mfc[m] * 0.5;
            double e0 = exp(-PI * bw / FS);
            double th = 2.0 * PI * mfc[m] / FS;
            C.bp_b0[m] = (float)(1.0 - e0);
            C.bp_cr[m] = (float)(e0 * cos(th));
            C.bp_ci[m] = (float)(e0 * sin(th));
            double eL  = exp(-PI * bw * (double)L_CHUNK / FS);       // chunk propagator
            double ang = th * (double)L_CHUNK;
            D.Pr[m] = eL * cos(ang);
            D.Pi[m] = eL * sin(ang);
            double eG  = exp(-PI * bw * (double)(L_CHUNK * GRP) / FS); // group propagator
            double angG = th * (double)(L_CHUNK * GRP);
            D15.Pr[m] = eG * cos(angG);
            D15.Pi[m] = eG * sin(angG);
        }
    }

    const int smem1 = ROWS_PER_BLK * XS_STRIDE * 4;                    // 33792 B
    const int smem3 = smem1 + 8 * 64 * TR_STRIDE * 4;                  // 74752 B
    dim3 grid(2, N_CHUNKS);
    mfb_chunk<false><<<grid, 512, smem1, stream>>>(x, C, ws_fin, nullptr, nullptr);
    mfb_groupsum<<<100, 256, 0, stream>>>(ws_fin, Agg, D);
    mfb_groupscan<<<4, 256, 0, stream>>>(Agg, Upre, D15);
    mfb_expand<<<100, 256, 0, stream>>>(ws_fin, Upre, ws_init, D);
    mfb_chunk<true><<<grid, 512, smem3, stream>>>(x, C, nullptr, ws_init, out);
}

// Round 8
// 69.836 us; speedup vs baseline: 4.6775x; 1.0136x over previous
//
#include <hip/hip_runtime.h>
#include <cmath>

#define T_LEN 48000
#define L_CHUNK 128
#define N_CHUNKS 375
#define N_ROWS 124
#define SLOTS 1024          // 8 channels * 128 padded rows
#define ROWS_PER_BLK 64
#define XS_STRIDE 132       // 128 + 4 pad floats: 528 B rows, 16B-aligned
#define TR_STRIDE 20        // 16 + 4 pad floats: 80 B rows, 16B-aligned
#define GRP 15              // chunks per group
#define NGRP 25             // groups: GRP * NGRP == N_CHUNKS

struct CoefF {
    float lp_b0, lp_b1, lp_b2, lp_a1, lp_a2;
    float bp_b0[7], bp_cr[7], bp_ci[7];
};
struct CoefD {
    double p00, p01, p10, p11;   // LP propagator (2x2)
    double Pr[7], Pi[7];         // resonator propagators (complex)
};

// Select per-channel propagator as real 2x2 (wave-uniform ch, static indices).
__device__ __forceinline__ void sel_M(int ch, const CoefD& D,
                                      double& m00, double& m01, double& m10, double& m11) {
    if (ch == 0) {
        m00 = D.p00; m01 = D.p01; m10 = D.p10; m11 = D.p11;
    } else {
        double Pr = 0.0, Pi = 0.0;
#pragma unroll
        for (int c = 1; c < 8; ++c) if (ch == c) { Pr = D.Pr[c - 1]; Pi = D.Pi[c - 1]; }
        m00 = Pr; m01 = -Pi; m10 = Pi; m11 = Pr;
    }
}

// Phase 1 (FINAL=false): zero-init chunk scan, write final state only.
// Phase 3 (FINAL=true):  derive chunk-init from U[group] + <=14-step prefix over
//                        ws_fin (fused expand), scan, transpose-store outputs.
template <bool FINAL>
__global__ __launch_bounds__(512) void mfb_chunk(const float* __restrict__ x,
                                                 CoefF C, CoefD D,
                                                 float2* __restrict__ ws_fin,
                                                 const float2* __restrict__ U,
                                                 float* __restrict__ out) {
    extern __shared__ __align__(16) float smem[];
    float* xs = smem;                                  // [64][XS_STRIDE]
    const int t     = threadIdx.x;                     // 0..511
    const int j     = blockIdx.y;                      // chunk index
    const int n0    = (int)blockIdx.x * ROWS_PER_BLK;
    const int tbase = j * L_CHUNK;

    // ---- stage x tile into LDS, float4 both sides ----
#pragma unroll
    for (int i = 0; i < 4; ++i) {
        int g = i * 512 + t;            // float4-granule 0..2047
        int r = g >> 5, c = (g & 31) * 4;
        int n = n0 + r;
        float4 v = make_float4(0.f, 0.f, 0.f, 0.f);
        if (n < N_ROWS)
            v = *reinterpret_cast<const float4*>(x + (size_t)n * T_LEN + tbase + c);
        *reinterpret_cast<float4*>(xs + r * XS_STRIDE + c) = v;
    }
    __syncthreads();

    const int ch   = t >> 6;        // wave-uniform channel
    const int nn   = t & 63;        // lane = stream within tile
    const int n    = n0 + nn;
    const int slot = ch * 128 + n;
    float* trw = smem + ROWS_PER_BLK * XS_STRIDE + ch * (64 * TR_STRIDE);

    float f_b0, f_b1 = 0.f, f_b2 = 0.f, f_a1 = 0.f, f_a2 = 0.f, f_cr = 0.f, f_ci = 0.f;
    if (ch == 0) {
        f_b0 = C.lp_b0; f_b1 = C.lp_b1; f_b2 = C.lp_b2; f_a1 = C.lp_a1; f_a2 = C.lp_a2;
    } else {
        f_b0 = 0.f;
#pragma unroll
        for (int c = 1; c < 8; ++c)
            if (ch == c) { f_b0 = C.bp_b0[c - 1]; f_cr = C.bp_cr[c - 1]; f_ci = C.bp_ci[c - 1]; }
    }
    const bool kp = (ch <= 2);

    float s0 = 0.f, s1 = 0.f;
    if (FINAL) {
        // ---- fused expand: init state = U[g] advanced i = j%GRP chunk steps ----
        const int g = j / GRP, i = j - g * GRP;   // block-uniform
        double m00, m01, m10, m11;
        sel_M(ch, D, m00, m01, m10, m11);
        float2 ug = U[(size_t)g * SLOTS + slot];
        double u0 = ug.x, u1 = ug.y;
        const float2* Fb = ws_fin + (size_t)(g * GRP) * SLOTS + slot;
        float2 f[GRP - 1];
#pragma unroll
        for (int k = 0; k < GRP - 1; ++k)
            f[k] = (k < i) ? Fb[(size_t)k * SLOTS] : make_float2(0.f, 0.f);
#pragma unroll
        for (int k = 0; k < GRP - 1; ++k)
            if (k < i) {
                double t0 = (double)f[k].x + m00 * u0 + m01 * u1;
                double t1 = (double)f[k].y + m10 * u0 + m11 * u1;
                u0 = t0; u1 = t1;
            }
        s0 = (float)u0; s1 = (float)u1;
    }

    for (int b = 0; b < L_CHUNK / 16; ++b) {
        float4 xv4[4];
#pragma unroll
        for (int q = 0; q < 4; ++q)
            xv4[q] = *reinterpret_cast<const float4*>(xs + nn * XS_STRIDE + b * 16 + q * 4);
        const float* xv = reinterpret_cast<const float*>(xv4);

        float buf[16];
        if (ch == 0) {
#pragma unroll
            for (int k = 0; k < 16; ++k) {
                float xvk = xv[k];
                float y  = fmaf(f_b0, xvk, s0);
                s0 = fmaf(f_b1, xvk, fmaf(-f_a1, y, s1));
                s1 = fmaf(f_b2, xvk, -f_a2 * y);
                if (FINAL) buf[k] = 2.0f * y;
            }
        } else {
#pragma unroll
            for (int k = 0; k < 16; ++k) {
                float xvk = xv[k];
                float nyr = fmaf(f_cr, s0, fmaf(-f_ci, s1, f_b0 * xvk));
                float nyi = fmaf(f_cr, s1, f_ci * s0);
                s0 = nyr; s1 = nyi;
                if (FINAL)
                    buf[k] = kp ? 2.0f * nyr : 2.0f * sqrtf(fmaf(nyr, nyr, nyi * nyi));
            }
        }

        if (FINAL) {
            // Per-wave transpose tile (trw is wave-private). The DS pipe is in-order
            // per wave, so cross-lane write->read through LDS needs only a COMPILER
            // reorder fence, not an lgkmcnt drain.
            asm volatile("" ::: "memory");
            *reinterpret_cast<float4*>(trw + nn * TR_STRIDE + 0)  = make_float4(buf[0], buf[1], buf[2], buf[3]);
            *reinterpret_cast<float4*>(trw + nn * TR_STRIDE + 4)  = make_float4(buf[4], buf[5], buf[6], buf[7]);
            *reinterpret_cast<float4*>(trw + nn * TR_STRIDE + 8)  = make_float4(buf[8], buf[9], buf[10], buf[11]);
            *reinterpret_cast<float4*>(trw + nn * TR_STRIDE + 12) = make_float4(buf[12], buf[13], buf[14], buf[15]);
            asm volatile("" ::: "memory");
#pragma unroll
            for (int s = 0; s < 4; ++s) {
                int rr = s * 16 + (nn >> 2);
                int kk = (nn & 3) * 4;
                int nrow = n0 + rr;
                if (nrow < N_ROWS) {
                    float4 v = *reinterpret_cast<const float4*>(trw + rr * TR_STRIDE + kk);
                    *reinterpret_cast<float4*>(out + (size_t)(nrow * 8 + ch) * T_LEN
                                               + tbase + b * 16 + kk) = v;
                }
            }
        }
    }
    if (!FINAL) ws_fin[(size_t)j * SLOTS + slot] = make_float2(s0, s1);
}

// ---- Tree combine, stage A: per (slot, group) aggregate A_g = sum M^(14-i) F_i ----
__global__ __launch_bounds__(256) void mfb_groupsum(const float2* __restrict__ ws_fin,
                                                    float2* __restrict__ A, CoefD D) {
    int tid = blockIdx.x * 256 + (int)threadIdx.x;   // 0..25599
    int s = tid & 1023, g = tid >> 10;
    double m00, m01, m10, m11;
    sel_M(s >> 7, D, m00, m01, m10, m11);

    const float2* base = ws_fin + (size_t)g * GRP * SLOTS + s;
    float2 f[GRP];
#pragma unroll
    for (int i = 0; i < GRP; ++i) f[i] = base[(size_t)i * SLOTS];

    double a0 = 0.0, a1 = 0.0;
#pragma unroll
    for (int i = 0; i < GRP; ++i) {
        double t0 = m00 * a0 + m01 * a1 + (double)f[i].x;
        double t1 = m10 * a0 + m11 * a1 + (double)f[i].y;
        a0 = t0; a1 = t1;
    }
    A[(size_t)g * SLOTS + s] = make_float2((float)a0, (float)a1);
}

// ---- stage B: per slot, exclusive prefix over 25 groups with M15 = M^(15*128) ----
__global__ __launch_bounds__(256) void mfb_groupscan(const float2* __restrict__ A,
                                                     float2* __restrict__ U, CoefD D15) {
    int s = blockIdx.x * 256 + (int)threadIdx.x;     // 0..1023
    double m00, m01, m10, m11;
    sel_M(s >> 7, D15, m00, m01, m10, m11);

    float2 f[NGRP];
#pragma unroll
    for (int g = 0; g < NGRP; ++g) f[g] = A[(size_t)g * SLOTS + s];

    double u0 = 0.0, u1 = 0.0;
#pragma unroll
    for (int g = 0; g < NGRP; ++g) {
        U[(size_t)g * SLOTS + s] = make_float2((float)u0, (float)u1);
        double t0 = (double)f[g].x + m00 * u0 + m01 * u1;
        double t1 = (double)f[g].y + m10 * u0 + m11 * u1;
        u0 = t0; u1 = t1;
    }
}

extern "C" void kernel_launch(void* const* d_in, const int* in_sizes, int n_in,
                              void* d_out, int out_size, void* d_ws, size_t ws_size,
                              hipStream_t stream) {
    const float* x = (const float*)d_in[0];
    float* out = (float*)d_out;
    char* ws = (char*)d_ws;
    float2* ws_fin  = (float2*)ws;                     // 3,072,000 B
    float2* Agg     = (float2*)(ws + 3072000);         //   204,800 B
    float2* Upre    = (float2*)(ws + 3276800);         //   204,800 B

    // ---- host-side coefficient computation (double, cast to f32 like the ref) ----
    const double PI = 3.141592653589793;
    const double FS = 16000.0;
    CoefF C; CoefD D, D15;
    {
        double K   = tan(PI * 2.5 / FS);
        double nrm = 1.0 / (1.0 + sqrt(2.0) * K + K * K);
        double a1  = 2.0 * (K * K - 1.0) * nrm;
        double a2  = (1.0 - sqrt(2.0) * K + K * K) * nrm;
        C.lp_b0 = (float)(K * K * nrm);
        C.lp_b1 = (float)(2.0 * K * K * nrm);
        C.lp_b2 = (float)(K * K * nrm);
        C.lp_a1 = (float)a1;
        C.lp_a2 = (float)a2;
        double p00 = -a1, p01 = 1.0, p10 = -a2, p11 = 0.0;
        for (int i = 0; i < 7; ++i) {   // A^128 by 7 squarings
            double q00 = p00 * p00 + p01 * p10, q01 = p00 * p01 + p01 * p11;
            double q10 = p10 * p00 + p11 * p10, q11 = p10 * p01 + p11 * p11;
            p00 = q00; p01 = q01; p10 = q10; p11 = q11;
        }
        D.p00 = p00; D.p01 = p01; D.p10 = p10; D.p11 = p11;
        // (A^128)^15 by square-and-multiply
        double r00 = 1, r01 = 0, r10 = 0, r11 = 1, b00 = p00, b01 = p01, b10 = p10, b11 = p11;
        for (int e = 15; e > 0; e >>= 1) {
            if (e & 1) {
                double q00 = r00 * b00 + r01 * b10, q01 = r00 * b01 + r01 * b11;
                double q10 = r10 * b00 + r11 * b10, q11 = r10 * b01 + r11 * b11;
                r00 = q00; r01 = q01; r10 = q10; r11 = q11;
            }
            double q00 = b00 * b00 + b01 * b10, q01 = b00 * b01 + b01 * b11;
            double q10 = b10 * b00 + b11 * b10, q11 = b10 * b01 + b11 * b11;
            b00 = q00; b01 = q01; b10 = q10; b11 = q11;
        }
        D15.p00 = r00; D15.p01 = r01; D15.p10 = r10; D15.p11 = r11;

        double rr = (1.0 + 1.0 / 4.0) / (1.0 - 1.0 / 4.0);   // 5/3
        double mfc[7]; mfc[0] = 5.0; mfc[1] = 10.0;
        double f = 10.0 * rr;
        for (int m = 2; m < 7; ++m) { mfc[m] = f; f *= rr; }
        for (int m = 0; m < 7; ++m) {
            double bw = (mfc[m] <= 10.0) ? 5.0 : mfc[m] * 0.5;
            double e0 = exp(-PI * bw / FS);
            double th = 2.0 * PI * mfc[m] / FS;
            C.bp_b0[m] = (float)(1.0 - e0);
            C.bp_cr[m] = (float)(e0 * cos(th));
            C.bp_ci[m] = (float)(e0 * sin(th));
            double eL  = exp(-PI * bw * (double)L_CHUNK / FS);       // chunk propagator
            double ang = th * (double)L_CHUNK;
            D.Pr[m] = eL * cos(ang);
            D.Pi[m] = eL * sin(ang);
            double eG  = exp(-PI * bw * (double)(L_CHUNK * GRP) / FS); // group propagator
            double angG = th * (double)(L_CHUNK * GRP);
            D15.Pr[m] = eG * cos(angG);
            D15.Pi[m] = eG * sin(angG);
        }
    }

    const int smem1 = ROWS_PER_BLK * XS_STRIDE * 4;                    // 33792 B
    const int smem3 = smem1 + 8 * 64 * TR_STRIDE * 4;                  // 74752 B
    dim3 grid(2, N_CHUNKS);
    mfb_chunk<false><<<grid, 512, smem1, stream>>>(x, C, D, ws_fin, nullptr, nullptr);
    mfb_groupsum<<<100, 256, 0, stream>>>(ws_fin, Agg, D);
    mfb_groupscan<<<4, 256, 0, stream>>>(Agg, Upre, D15);
    mfb_chunk<true><<<grid, 512, smem3, stream>>>(x, C, D, ws_fin, Upre, out);
}